// Round 4
// baseline (204.672 us; speedup 1.0000x reference)
//
#include <hip/hip_runtime.h>
#include <hip/hip_bf16.h>

#define S_TOK 8192
#define NEXP 64
#define MDIM 1024
#define CAP 128
#define NCH 1024
#define CHUNK 8    // tokens per gate block
#define TPW 2      // tokens per wave

// flat output element offsets (fp32)
#define OFF2 67108865    // dispatch_mask start  (1 + 8192*64*128)
#define OFF3 134217729   // mask1 start
#define OFF4 134742017   // exp_counts start
#define OFF5 134742081   // indices1_s start
#define OUT_ELEMS 134750273
#define FILL_SLOTS 33687568   // (OUT_ELEMS-1)/4

// ---------------- Kernel A: pure streaming zero-fill of the ENTIRE output.
// Mirrors __amd_rocclr_fillBufferAligned's regime: grid-stride, no loads,
// no value computation. Everything else overwrites on top of this.
__global__ __launch_bounds__(256) void fill_kernel(float* __restrict__ out)
{
  const int tid = blockIdx.x * 256 + threadIdx.x;
  const int stride = 2048 * 256;
  float4* o4 = reinterpret_cast<float4*>(out);
  const float4 z = make_float4(0.f, 0.f, 0.f, 0.f);
  for (int j = tid; j < FILL_SLOTS; j += stride) o4[j] = z;
  if (tid == 0) out[OUT_ELEMS - 1] = 0.f;
}

// ---------------- Kernel B: gate (logits GEMM + softmax + argmax + chunk ranks)
// x staged via LDS with coalesced float4 loads; compute reads LDS broadcasts.
__global__ __launch_bounds__(256) void gate_kernel(
    const float* __restrict__ x, const float* __restrict__ wg,
    unsigned char* __restrict__ ind, unsigned char* __restrict__ rnk,
    float* __restrict__ gval, unsigned char* __restrict__ counts,
    float* __restrict__ gparts)
{
  __shared__ float sx[CHUNK][MDIM];      // 32 KB
  __shared__ float s_gsum[4][64];
  __shared__ int s_ind[CHUNK];
  const int b = blockIdx.x;
  const int lane = threadIdx.x & 63;     // expert
  const int wv = threadIdx.x >> 6;       // wave 0..3

  // coalesced stage: 2048 float4 per block, 8 per thread
  const float4* x4 = reinterpret_cast<const float4*>(x) + (size_t)b * (CHUNK * MDIM / 4);
  float4* sx4 = reinterpret_cast<float4*>(&sx[0][0]);
#pragma unroll
  for (int i = 0; i < CHUNK * MDIM / 4 / 256; ++i)
    sx4[i * 256 + threadIdx.x] = x4[i * 256 + threadIdx.x];
  __syncthreads();

  const int t0 = wv * TPW;
  float acc[TPW] = {0.f, 0.f};
#pragma unroll 2
  for (int d = 0; d < MDIM; d += 4) {
    const float w0 = wg[(d + 0) * NEXP + lane];
    const float w1 = wg[(d + 1) * NEXP + lane];
    const float w2 = wg[(d + 2) * NEXP + lane];
    const float w3 = wg[(d + 3) * NEXP + lane];
#pragma unroll
    for (int t = 0; t < TPW; ++t) {
      const float4 xv = reinterpret_cast<const float4*>(&sx[t0 + t][0])[d >> 2];
      acc[t] = fmaf(xv.x, w0, acc[t]);
      acc[t] = fmaf(xv.y, w1, acc[t]);
      acc[t] = fmaf(xv.z, w2, acc[t]);
      acc[t] = fmaf(xv.w, w3, acc[t]);
    }
  }

  float colsum = 0.f;
#pragma unroll
  for (int t = 0; t < TPW; ++t) {
    const float logit = acc[t];
    float m = logit;
#pragma unroll
    for (int off = 32; off > 0; off >>= 1) m = fmaxf(m, __shfl_xor(m, off, 64));
    const float ex = __expf(logit - m);
    float sm = ex;
#pragma unroll
    for (int off = 32; off > 0; off >>= 1) sm += __shfl_xor(sm, off, 64);
    colsum += ex / sm;                   // this lane's gate for this token
    const unsigned long long bal = __ballot(logit == m);
    const int widx = (int)(__ffsll(bal) - 1);   // lowest max lane == argmax tie-break
    if (lane == 0) {
      const int tk = b * CHUNK + t0 + t;
      ind[tk] = (unsigned char)widx;
      gval[tk] = 1.0f / sm;              // winning gate = exp(0)/sum
      s_ind[t0 + t] = widx;
    }
  }
  s_gsum[wv][lane] = colsum;
  __syncthreads();
  if (wv == 0) {
    const float g = s_gsum[0][lane] + s_gsum[1][lane] + s_gsum[2][lane] + s_gsum[3][lane];
    gparts[b * NEXP + lane] = g;
    int cnt = 0;                         // deterministic within-chunk rank
#pragma unroll
    for (int t = 0; t < CHUNK; ++t) {
      const int e = s_ind[t];
      const int r = __shfl(cnt, e, 64);
      if (lane == 0) rnk[b * CHUNK + t] = (unsigned char)r;
      cnt += (lane == e) ? 1 : 0;
    }
    counts[b * NEXP + lane] = (unsigned char)cnt;
  }
}

// ---------------- Kernel C: per-expert prefix over 1024 chunks (16 groups x 64)
// + exp_counts + l_aux. Runs AFTER fill, so its out[] writes stand.
__global__ __launch_bounds__(1024) void reduce_kernel(
    const unsigned char* __restrict__ counts, const float* __restrict__ gparts,
    unsigned short* __restrict__ offs, float* __restrict__ out)
{
  __shared__ int s_cnt[16][64];
  __shared__ float s_gs[16][64];
  const int e = threadIdx.x & 63;
  const int g = threadIdx.x >> 6;        // group 0..15, 64 chunks each
  const int ch0 = g * 64;

  int csum = 0; float gsum = 0.f;
#pragma unroll 8
  for (int ch = ch0; ch < ch0 + 64; ++ch) {
    csum += (int)counts[ch * NEXP + e];
    gsum += gparts[ch * NEXP + e];
  }
  s_cnt[g][e] = csum; s_gs[g][e] = gsum;
  __syncthreads();

  int base = 0;
  for (int k = 0; k < g; ++k) base += s_cnt[k][e];
  int run = base;
#pragma unroll 8
  for (int ch = ch0; ch < ch0 + 64; ++ch) {
    offs[ch * NEXP + e] = (unsigned short)run;   // exclusive prefix per expert
    run += (int)counts[ch * NEXP + e];
  }
  if (g == 15) {
    const int total = run;
    out[OFF4 + e] = (float)total;
    float gtot = 0.f;
#pragma unroll
    for (int k = 0; k < 16; ++k) gtot += s_gs[k][e];
    const float me = gtot * (1.0f / (float)S_TOK);
    const float ce = (float)total * (1.0f / (float)S_TOK);
    float prod = me * ce;
#pragma unroll
    for (int off = 32; off > 0; off >>= 1) prod += __shfl_xor(prod, off, 64);
    if (e == 0) out[0] = prod * (float)NEXP;     // l_aux
  }
}

// ---------------- Kernel D: scatter the nonzeros into the zeroed field.
__global__ __launch_bounds__(256) void scatter_kernel(
    const unsigned char* __restrict__ ind, const unsigned char* __restrict__ rnk,
    const unsigned short* __restrict__ offs, const float* __restrict__ gval,
    float* __restrict__ out)
{
  const int s = blockIdx.x * 256 + threadIdx.x;
  if (s >= S_TOK) return;
  const int e = (int)ind[s];
  const int loc = (int)offs[(s >> 3) * NEXP + e] + (int)rnk[s];
  out[OFF5 + s] = (float)e;                      // indices1_s
  out[OFF3 + (s << 6) + e] = 1.0f;               // mask1
  if (loc < CAP) {
    const int rel = (s << 13) + (e << 7) + loc;  // s*8192 + e*128 + loc
    out[1 + rel] = gval[s];                      // combine_weights
    out[OFF2 + rel] = 1.0f;                      // dispatch_mask
  }
}

extern "C" void kernel_launch(void* const* d_in, const int* in_sizes, int n_in,
                              void* d_out, int out_size, void* d_ws, size_t ws_size,
                              hipStream_t stream)
{
  const float* x = (const float*)d_in[0];
  const float* wg = (const float*)d_in[1];
  float* out = (float*)d_out;

  // ws layout, 496 KB total (f32 first for alignment)
  float* gval = (float*)d_ws;                          // 8192 f32      (32 KB)
  float* gparts = gval + S_TOK;                        // 1024*64 f32   (256 KB)
  unsigned short* offs = (unsigned short*)(gparts + NCH * NEXP);  // 1024*64 u16 (128 KB)
  unsigned char* ind = (unsigned char*)(offs + NCH * NEXP);       // 8192 u8
  unsigned char* rnk = ind + S_TOK;                    // 8192 u8
  unsigned char* counts = rnk + S_TOK;                 // 1024*64 u8    (64 KB)

  fill_kernel<<<2048, 256, 0, stream>>>(out);
  gate_kernel<<<NCH, 256, 0, stream>>>(x, wg, ind, rnk, gval, counts, gparts);
  reduce_kernel<<<1, 1024, 0, stream>>>(counts, gparts, offs, out);
  scatter_kernel<<<(S_TOK + 255) / 256, 256, 0, stream>>>(ind, rnk, offs, gval, out);
}

// Round 5
// 160.961 us; speedup vs baseline: 1.2716x; 1.2716x over previous
//
#include <hip/hip_runtime.h>
#include <hip/hip_bf16.h>

#define S_TOK 8192
#define NEXP 64
#define MDIM 1024
#define CAP 128
#define NCH 512
#define CHUNK 16        // tokens per gate block
#define DT 256          // d-rows per LDS wg tile
#define NPH 4           // MDIM / DT

// flat output element offsets (fp32)
#define OFF2 67108865    // dispatch_mask start  (1 + 8192*64*128)
#define OFF3 134217729   // mask1 start
#define OFF4 134742017   // exp_counts start
#define OFF5 134742081   // indices1_s start

// ---------------- Gate: logits GEMM (wg staged in LDS once per block) +
// softmax + argmax + per-chunk ranks. Lane l: token lt=l>>4, experts 4*(l&15)..+3.
__global__ __launch_bounds__(256) void gate_kernel(
    const float* __restrict__ x, const float* __restrict__ wg,
    unsigned char* __restrict__ ind, unsigned char* __restrict__ rnk,
    float* __restrict__ gval, unsigned char* __restrict__ counts,
    float* __restrict__ gparts)
{
  __shared__ float wgt[DT * NEXP];        // 64 KB wg tile
  __shared__ float g_all[CHUNK][NEXP];    // 4 KB gates for l_aux colsums
  __shared__ int s_ind[CHUNK];
  const int b = blockIdx.x;
  const int tid = threadIdx.x;
  const int lane = tid & 63;
  const int wv = tid >> 6;                // wave 0..3
  const int lt = lane >> 4;               // token within wave (0..3)
  const int eg = lane & 15;               // expert group -> experts 4eg..4eg+3
  const int tk = b * CHUNK + wv * 4 + lt; // global token

  const float4* x4 = reinterpret_cast<const float4*>(x);
  const float4* wg4 = reinterpret_cast<const float4*>(wg);
  float4* wl4 = reinterpret_cast<float4*>(wgt);

  float acc0 = 0.f, acc1 = 0.f, acc2 = 0.f, acc3 = 0.f;
#pragma unroll
  for (int p = 0; p < NPH; ++p) {
    // stage 64 KB of wg (rows p*DT .. p*DT+DT), fully coalesced
#pragma unroll
    for (int i = 0; i < DT * NEXP / 4 / 256; ++i)     // 16 float4/thread
      wl4[i * 256 + tid] = wg4[p * (DT * NEXP / 4) + i * 256 + tid];
    __syncthreads();

    const int xbase = tk * (MDIM / 4) + p * (DT / 4);
#pragma unroll 2
    for (int dq = 0; dq < DT / 4; ++dq) {             // 64 iters
      const float4 xv = x4[xbase + dq];
      {
        const float4 w = wl4[(4 * dq + 0) * 16 + eg];
        acc0 = fmaf(xv.x, w.x, acc0); acc1 = fmaf(xv.x, w.y, acc1);
        acc2 = fmaf(xv.x, w.z, acc2); acc3 = fmaf(xv.x, w.w, acc3);
      }
      {
        const float4 w = wl4[(4 * dq + 1) * 16 + eg];
        acc0 = fmaf(xv.y, w.x, acc0); acc1 = fmaf(xv.y, w.y, acc1);
        acc2 = fmaf(xv.y, w.z, acc2); acc3 = fmaf(xv.y, w.w, acc3);
      }
      {
        const float4 w = wl4[(4 * dq + 2) * 16 + eg];
        acc0 = fmaf(xv.z, w.x, acc0); acc1 = fmaf(xv.z, w.y, acc1);
        acc2 = fmaf(xv.z, w.z, acc2); acc3 = fmaf(xv.z, w.w, acc3);
      }
      {
        const float4 w = wl4[(4 * dq + 3) * 16 + eg];
        acc0 = fmaf(xv.w, w.x, acc0); acc1 = fmaf(xv.w, w.y, acc1);
        acc2 = fmaf(xv.w, w.z, acc2); acc3 = fmaf(xv.w, w.w, acc3);
      }
    }
    __syncthreads();   // protect tile before next stage
  }

  // local argmax (lowest expert wins ties)
  float m = acc0; int ei = eg * 4;
  if (acc1 > m) { m = acc1; ei = eg * 4 + 1; }
  if (acc2 > m) { m = acc2; ei = eg * 4 + 2; }
  if (acc3 > m) { m = acc3; ei = eg * 4 + 3; }
#pragma unroll
  for (int off = 1; off <= 8; off <<= 1) {
    const float om = __shfl_xor(m, off, 64);
    const int oe = __shfl_xor(ei, off, 64);
    if (om > m || (om == m && oe < ei)) { m = om; ei = oe; }
  }
  const float e0 = __expf(acc0 - m), e1 = __expf(acc1 - m),
              e2 = __expf(acc2 - m), e3 = __expf(acc3 - m);
  float sm = e0 + e1 + e2 + e3;
#pragma unroll
  for (int off = 1; off <= 8; off <<= 1) sm += __shfl_xor(sm, off, 64);
  const float inv = 1.0f / sm;

  *reinterpret_cast<float4*>(&g_all[wv * 4 + lt][eg * 4]) =
      make_float4(e0 * inv, e1 * inv, e2 * inv, e3 * inv);
  if (eg == 0) {
    s_ind[wv * 4 + lt] = ei;
    ind[tk] = (unsigned char)ei;
    gval[tk] = inv;                       // winner gate = exp(0)/sum
  }
  __syncthreads();

  if (wv == 0) {                          // lane = expert
    float colsum = 0.f;
#pragma unroll
    for (int t = 0; t < CHUNK; ++t) colsum += g_all[t][lane];
    gparts[b * NEXP + lane] = colsum;
    int cnt = 0;                          // deterministic within-chunk rank
#pragma unroll
    for (int t = 0; t < CHUNK; ++t) {
      const int e = s_ind[t];
      const int r = __shfl(cnt, e, 64);
      if (lane == 0) rnk[b * CHUNK + t] = (unsigned char)r;
      cnt += (lane == e) ? 1 : 0;
    }
    counts[b * NEXP + lane] = (unsigned char)cnt;
  }
}

// ---------------- Reduce: per-expert prefix over 512 chunks (16 groups x 32)
__global__ __launch_bounds__(1024) void reduce_kernel(
    const unsigned char* __restrict__ counts, const float* __restrict__ gparts,
    unsigned short* __restrict__ offs, float* __restrict__ out)
{
  __shared__ int s_cnt[16][64];
  __shared__ float s_gs[16][64];
  const int e = threadIdx.x & 63;
  const int g = threadIdx.x >> 6;         // group 0..15, 32 chunks each
  const int ch0 = g * 32;

  int csum = 0; float gsum = 0.f;
#pragma unroll 8
  for (int ch = ch0; ch < ch0 + 32; ++ch) {
    csum += (int)counts[ch * NEXP + e];
    gsum += gparts[ch * NEXP + e];
  }
  s_cnt[g][e] = csum; s_gs[g][e] = gsum;
  __syncthreads();

  int base = 0;
  for (int k = 0; k < g; ++k) base += s_cnt[k][e];
  int run = base;
#pragma unroll 8
  for (int ch = ch0; ch < ch0 + 32; ++ch) {
    offs[ch * NEXP + e] = (unsigned short)run;   // exclusive per-expert prefix
    run += (int)counts[ch * NEXP + e];
  }
  if (g == 15) {
    const int total = run;
    out[OFF4 + e] = (float)total;
    float gtot = 0.f;
#pragma unroll
    for (int k = 0; k < 16; ++k) gtot += s_gs[k][e];
    const float me = gtot * (1.0f / (float)S_TOK);
    const float ce = (float)total * (1.0f / (float)S_TOK);
    float prod = me * ce;
#pragma unroll
    for (int off = 32; off > 0; off >>= 1) prod += __shfl_xor(prod, off, 64);
    if (e == 0) out[0] = prod * (float)NEXP;     // l_aux
  }
}

// ---------------- Scatter: nonzeros into the memset-zeroed field
__global__ __launch_bounds__(256) void scatter_kernel(
    const unsigned char* __restrict__ ind, const unsigned char* __restrict__ rnk,
    const unsigned short* __restrict__ offs, const float* __restrict__ gval,
    float* __restrict__ out)
{
  const int s = blockIdx.x * 256 + threadIdx.x;
  if (s >= S_TOK) return;
  const int e = (int)ind[s];
  const int loc = (int)offs[(s >> 4) * NEXP + e] + (int)rnk[s];
  out[OFF5 + s] = (float)e;                      // indices1_s
  out[OFF3 + (s << 6) + e] = 1.0f;               // mask1
  if (loc < CAP) {
    const int rel = (s << 13) + (e << 7) + loc;  // s*8192 + e*128 + loc
    out[1 + rel] = gval[s];                      // combine_weights
    out[OFF2 + rel] = 1.0f;                      // dispatch_mask
  }
}

extern "C" void kernel_launch(void* const* d_in, const int* in_sizes, int n_in,
                              void* d_out, int out_size, void* d_ws, size_t ws_size,
                              hipStream_t stream)
{
  const float* x = (const float*)d_in[0];
  const float* wg = (const float*)d_in[1];
  float* out = (float*)d_out;

  // ws layout (~272 KB)
  float* gval = (float*)d_ws;                                     // 8192 f32
  float* gparts = gval + S_TOK;                                   // 512*64 f32
  unsigned short* offs = (unsigned short*)(gparts + NCH * NEXP);  // 512*64 u16
  unsigned char* ind = (unsigned char*)(offs + NCH * NEXP);       // 8192 u8
  unsigned char* rnk = ind + S_TOK;                               // 8192 u8
  unsigned char* counts = rnk + S_TOK;                            // 512*64 u8

  hipMemsetAsync(out, 0, (size_t)out_size * sizeof(float), stream);
  gate_kernel<<<NCH, 256, 0, stream>>>(x, wg, ind, rnk, gval, counts, gparts);
  reduce_kernel<<<1, 1024, 0, stream>>>(counts, gparts, offs, out);
  scatter_kernel<<<(S_TOK + 255) / 256, 256, 0, stream>>>(ind, rnk, offs, gval, out);
}